// Round 17
// baseline (197.284 us; speedup 1.0000x reference)
//
#include <hip/hip_runtime.h>

#define CC   256
#define HH   56
#define WWID 56
#define KIN1 1608
#define KP1  1632
#define NO1  72
#define NO2  288
#define PPB  14
#define H2   112
#define W2D  112

typedef unsigned short u16;
typedef unsigned int   u32;
typedef __attribute__((ext_vector_type(8))) short v8s;
typedef __attribute__((ext_vector_type(4))) float v4f;
typedef __attribute__((ext_vector_type(2))) float v2f;
typedef __attribute__((ext_vector_type(4))) unsigned short us4;

#define W1BF_ELEMS (80 * KP1)
#define W2BF_OFF_B 262144

// LDS layout (bytes). Total 32768. R17 = R16 (best, ~89us steady) + f32 window
// registers: drop the bf16 pack (24 cvtpk in P1) + unpack (~130 VALU in P7) of
// win_p; keep staged window as float win_f[3][16] (it IS sc -- zero copy) and
// P7 indexes win_f[r][n+kj] directly. +24 VGPR (60 -> ~85, cap 128, occupancy
// VGPR-insensitive per R9/R10 ledger); numerics move toward f32 reference.
#define LDS_TOTAL 32768
#define OFF_A 0        // rowmaxT [14][768] u16 (21504) -> partials [4][5][16][16] f32 (20480)
                       //   -> y2L [16][300] f32 (19200) -> tile [128][60] f32 (30720, spans A..C)
#define OFF_B 21504    // colmaxT [16][256] u16 (8192); overrun reads land in C (defined, discarded)
#define OFF_C 29696    // x1T / y1b [16][96] u16 (3072)

#define Y2S 300        // y2L row stride (f32): 300%32=12 -> rows spread over 8 banks

#define SWZ(row) (((row) & 7) << 3)   // u16-element XOR key per LDS row

__device__ __forceinline__ u16 f2b(float x) {
  u32 u = __float_as_uint(x);
  u = (u + 0x7FFFu + ((u >> 16) & 1u)) >> 16;   // RNE fp32->bf16
  return (u16)u;
}

// HW packed fp32->bf16 (RNE): dst[15:0]=cvt(lo), dst[31:16]=cvt(hi). 1 VALU op.
__device__ __forceinline__ u32 cvtpk(float lo, float hi) {
  u32 r;
  asm("v_cvt_pk_bf16_f32 %0, %1, %2" : "=v"(r) : "v"(lo), "v"(hi));
  return r;
}

// LDS-only barrier: no vmcnt drain (global stores stay in flight).
#define BARRIER_LDS()                                         \
  do {                                                        \
    asm volatile("s_waitcnt lgkmcnt(0)" ::: "memory");        \
    __builtin_amdgcn_s_barrier();                             \
    __builtin_amdgcn_sched_barrier(0);                        \
  } while (0)

// DPP max step on the VALU pipe (fuses to v_max_f32_dpp). ctrl literal.
#define DPPMAX(m, ctrl)                                                          \
  do {                                                                           \
    int _y = __builtin_amdgcn_update_dpp(0, __float_as_int(m), (ctrl), 0xF, 0xF, false); \
    (m) = fmaxf((m), __int_as_float(_y));                                        \
  } while (0)

// ---- weight conversion; W1 columns PERMUTED to K-layout:
//   phys [0,768)    = x2 region: kj*256 + c      <- orig 72 + c*3 + kj
//   phys [768,1536) = x3 region: r*256 + c       <- orig 840 + c*3 + r
//   phys [1536,1632)= x1 region: m72 (<72), pad  <- orig m72
__global__ void kConvW(const float* __restrict__ W1, const float* __restrict__ W2,
                       u16* __restrict__ w1bf, u16* __restrict__ w2bf) {
  int p = blockIdx.x * 256 + threadIdx.x;   // pair index
  int e0 = 2 * p;
  float v0 = 0.f, v1 = 0.f;
  if (e0 < W1BF_ELEMS) {
    int m = e0 / KP1, k = e0 - m * KP1;
    if (m < NO1) {
      const float* Wm = W1 + m * KIN1;
      if (k < 768) {
        int o = 72 + (k & 255) * 3 + (k >> 8);
        v0 = Wm[o]; v1 = Wm[o + 3];
      } else if (k < 1536) {
        int o = 840 + (k & 255) * 3 + ((k - 768) >> 8);
        v0 = Wm[o]; v1 = Wm[o + 3];
      } else {
        int t1 = k - 1536;
        if (t1 < NO1)     v0 = Wm[t1];
        if (t1 + 1 < NO1) v1 = Wm[t1 + 1];
      }
    }
    ((u32*)w1bf)[p] = (u32)f2b(v0) | ((u32)f2b(v1) << 16);
  } else {
    int i2 = e0 - W1BF_ELEMS;
    if (i2 < NO2 * 96) {
      int m = i2 / 96, k = i2 - m * 96;
      if (k < NO1) {
        v0 = W2[m * NO1 + k];
        if (k + 1 < NO1) v1 = W2[m * NO1 + k + 1];
      }
      ((u32*)w2bf)[i2 >> 1] = (u32)f2b(v0) | ((u32)f2b(v1) << 16);
    }
  }
}

__global__ __launch_bounds__(256, 4)
void kFused(const float* __restrict__ in, const u16* __restrict__ w1bf,
            const float* __restrict__ b1, const u16* __restrict__ w2bf,
            const float* __restrict__ b2, float* __restrict__ out) {
  __shared__ __align__(16) char lds[LDS_TOTAL];
  u16*   rowmaxT = (u16*)(lds + OFF_A);
  u16*   colmaxT = (u16*)(lds + OFF_B);
  u16*   x1T     = (u16*)(lds + OFF_C);   // later aliased as y1b
  float* partA   = (float*)(lds + OFF_A); // partials, then y2L
  float* y2L     = (float*)(lds + OFF_A);
  float* tile    = (float*)(lds + OFF_A); // out transpose [128][60] f32 (after P7 barrier)

  const int t  = threadIdx.x;
  // ---- XCD-aware block remap (round-2 win): XCD k owns batch b=k.
  const int L  = blockIdx.x + 4 * (blockIdx.y + 56 * blockIdx.z);
  const int jq = L >> 3;
  const int jt = jq & 3, i = jq >> 2, b = L & 7;
  const int c  = t;
  const int g  = c >> 5;
  const int gc = c & 31;
  const int w  = t >> 6, lane = t & 63;
  const int ml = lane & 15, quad = lane >> 4;

  // ---- zero x1T pads (swizzled): cols[72,96) rows 0..15, rows 14,15 cols[0,72).
  {
    u32* xu = (u32*)x1T;   // row stride 48 u32; u32-level XOR key = (row&7)<<2
    if (t < 132) {
#pragma unroll
      for (int rp2 = 0; rp2 < 2; ++rp2) {
        int idx = 2 * t + rp2;
        if (idx < 192) {
          int row = idx / 12;
          xu[(row * 48 + 36 + (idx - row * 12)) ^ ((row & 7) << 2)] = 0u;
        } else {
          int e = idx - 192, row = 14 + e / 36;
          xu[(row * 48 + (e % 36)) ^ ((row & 7) << 2)] = 0u;
        }
      }
    }
  }

  // ---------------- P1: ALL 3 rows' loads issued first (latency overlap), then process ----------------
  const float* rowbase0 = in + ((size_t)b * CC + c) * (HH * WWID);
  float l3[3][20];
#pragma unroll
  for (int r = 0; r < 3; ++r) {
    const int row = i - 1 + r;
    if (row < 0 || row >= HH) {
#pragma unroll
      for (int k = 0; k < 20; ++k) l3[r][k] = 0.f;
    } else {
      const float* rp = rowbase0 + row * WWID;
      if (jt == 0) {
        *(float4*)&l3[r][0]  = *(const float4*)(rp);
        *(float4*)&l3[r][4]  = *(const float4*)(rp + 4);
        *(float4*)&l3[r][8]  = *(const float4*)(rp + 8);
        *(float4*)&l3[r][12] = *(const float4*)(rp + 12);
        l3[r][16] = l3[r][17] = l3[r][18] = l3[r][19] = 0.f;
      } else if (jt == 3) {
        const float* q = rp + 40;
        *(float4*)&l3[r][0]  = *(const float4*)(q);
        *(float4*)&l3[r][4]  = *(const float4*)(q + 4);
        *(float4*)&l3[r][8]  = *(const float4*)(q + 8);
        *(float4*)&l3[r][12] = *(const float4*)(q + 12);
        l3[r][16] = l3[r][17] = l3[r][18] = l3[r][19] = 0.f;
      } else {
        const float* q = rp + ((jt == 1) ? 12 : 24);
        *(float4*)&l3[r][0]  = *(const float4*)(q);
        *(float4*)&l3[r][4]  = *(const float4*)(q + 4);
        *(float4*)&l3[r][8]  = *(const float4*)(q + 8);
        *(float4*)&l3[r][12] = *(const float4*)(q + 12);
        *(float4*)&l3[r][16] = *(const float4*)(q + 16);
      }
    }
  }

  float win_f[3][16];   // staged window, f32, live through P7 (no bf16 round-trip)
  float colmax[16];
#pragma unroll
  for (int k = 0; k < 16; ++k) colmax[k] = -3.0e38f;

#pragma unroll
  for (int r = 0; r < 3; ++r) {
    float* sc = win_f[r];
    if (jt == 0) {
      sc[0] = 0.f;
#pragma unroll
      for (int k = 1; k < 16; ++k) sc[k] = l3[r][k - 1];
    } else if (jt == 3) {
#pragma unroll
      for (int k = 0; k < 15; ++k) sc[k] = l3[r][k + 1];
      sc[15] = 0.f;
    } else if (jt == 1) {
#pragma unroll
      for (int k = 0; k < 16; ++k) sc[k] = l3[r][k + 1];
    } else {
#pragma unroll
      for (int k = 0; k < 16; ++k) sc[k] = l3[r][k + 3];
    }
    // colmax accumulate (x2 source: max over window rows = di axis)
#pragma unroll
    for (int k = 0; k < 16; ++k) colmax[k] = fmaxf(colmax[k], sc[k]);
    // rowmax (x3): sliding max over dj, bf16 transposed [n][r*256+c], swizzled
#pragma unroll
    for (int n = 0; n < 14; ++n) {
      float v = fmaxf(fmaxf(sc[n], sc[n + 1]), sc[n + 2]);
      rowmaxT[(n * 768 + r * 256 + c) ^ SWZ(n)] = (u16)cvtpk(v, v);
    }
    // x1 stage: 32-channel group max. DPP levels (VALU pipe) + one ds_swizzle.
#pragma unroll
    for (int col = 0; col < 16; ++col) {
      float m = sc[col];
      DPPMAX(m, 0xB1);   // quad_perm [1,0,3,2] : lane ^ 1
      DPPMAX(m, 0x4E);   // quad_perm [2,3,0,1] : lane ^ 2
      DPPMAX(m, 0x141);  // row_half_mirror     : merges 4-groups -> 8-group
      DPPMAX(m, 0x140);  // row_mirror          : merges 8-groups -> 16-group
      { int y = __builtin_amdgcn_ds_swizzle(__float_as_int(m), 0x401F);  // lane ^ 16
        m = fmaxf(m, __int_as_float(y)); }
      if (gc == col) {
        u16 mv = (u16)cvtpk(m, m);
#pragma unroll
        for (int kj = 0; kj < 3; ++kj) {
          const int n = col - kj;
          if (n >= 0 && n < 14)
            x1T[(n * 96 + g * 9 + r * 3 + kj) ^ SWZ(n)] = mv;
        }
      }
    }
  }
  // colmaxT write: [col][c], swizzled
#pragma unroll
  for (int col = 0; col < 16; ++col)
    colmaxT[(col * 256 + c) ^ SWZ(col)] = (u16)cvtpk(colmax[col], colmax[col]);
  __syncthreads();

  // ---------------- P2: conv1 MFMA, compile-time K-split per wave ----------------
  v4f acc[5];
#pragma unroll
  for (int mt = 0; mt < 5; ++mt) acc[mt] = (v4f){0.f, 0.f, 0.f, 0.f};

  auto loadB = [&](int ks) -> v8s {
    if (ks < 24) {
      int kj = ks >> 3, c0 = (ks & 7) * 32, rowi = ml + kj;
      return *(v8s*)&colmaxT[(rowi * 256 + c0 + quad * 8) ^ SWZ(rowi)];
    } else if (ks < 48) {
      return *(v8s*)&rowmaxT[(ml * 768 + (ks - 24) * 32 + quad * 8) ^ SWZ(ml)];
    } else {
      return *(v8s*)&x1T[(ml * 96 + (ks - 48) * 32 + quad * 8) ^ SWZ(ml)];
    }
  };

  // Literal bounds -> full unroll; loadB region branches fold; LDS/global
  // addresses become base + compile-time immediates; scheduler pipelines loads.
#define P2_RUN(KS0, KS1)                                                         \
  {                                                                              \
    v8s bf_c = loadB(KS0);                                                       \
    v8s af_c[5];                                                                 \
    _Pragma("unroll")                                                            \
    for (int mt = 0; mt < 5; ++mt)                                               \
      af_c[mt] = *(const v8s*)&w1bf[(mt * 16 + ml) * KP1 + (KS0) * 32 + quad * 8]; \
    _Pragma("unroll")                                                            \
    for (int ks = KS0; ks < KS1; ++ks) {                                         \
      v8s bf_n, af_n[5];                                                         \
      if (ks + 1 < KS1) {                                                        \
        bf_n = loadB(ks + 1);                                                    \
        _Pragma("unroll")                                                        \
        for (int mt = 0; mt < 5; ++mt)                                           \
          af_n[mt] = *(const v8s*)&w1bf[(mt * 16 + ml) * KP1 + (ks + 1) * 32 + quad * 8]; \
      }                                                                          \
      __builtin_amdgcn_s_setprio(1);                                             \
      _Pragma("unroll")                                                          \
      for (int mt = 0; mt < 5; ++mt)                                             \
        acc[mt] = __builtin_amdgcn_mfma_f32_16x16x32_bf16(af_c[mt], bf_c, acc[mt], 0, 0, 0); \
      __builtin_amdgcn_s_setprio(0);                                             \
      if (ks + 1 < KS1) {                                                        \
        bf_c = bf_n;                                                             \
        _Pragma("unroll")                                                        \
        for (int mt = 0; mt < 5; ++mt) af_c[mt] = af_n[mt];                      \
      }                                                                          \
    }                                                                            \
  }

  if (w == 0)      { P2_RUN(0, 13)  }
  else if (w == 1) { P2_RUN(13, 26) }
  else if (w == 2) { P2_RUN(26, 39) }
  else             { P2_RUN(39, 51) }
#undef P2_RUN
  __syncthreads();                // all LDS reads of colmaxT/rowmaxT/x1T complete

  // ---------------- P3: partials to LDS (aliases rowmaxT) ----------------
#pragma unroll
  for (int mt = 0; mt < 5; ++mt)
    *(v4f*)&partA[((w * 5 + mt) * 16 + ml) * 16 + quad * 4] = acc[mt];
  __syncthreads();

  // ---------------- P4: vectorized reduce -> y1b bf16 [n][96] (aliases x1T) ----------------
  u16* y1b = x1T;
  if (t < 252) {
    const int mb = t / 14, n = t - mb * 14;
    v4f s = *(const v4f*)(b1 + mb * 4);      // mb*4+3 <= 71 < 72
#pragma unroll
    for (int ww = 0; ww < 4; ++ww) {
      v4f p = *(v4f*)&partA[((ww * 5 + (mb >> 2)) * 16 + n) * 16 + (mb & 3) * 4];
      s[0] += p[0]; s[1] += p[1]; s[2] += p[2]; s[3] += p[3];
    }
    const u32 lo = cvtpk(s[0], s[1]), hi = cvtpk(s[2], s[3]);
    us4 h;
    h.x = (u16)lo; h.y = (u16)(lo >> 16); h.z = (u16)hi; h.w = (u16)(hi >> 16);
    *(us4*)&y1b[(n * 96 + mb * 4) ^ SWZ(n)] = h;   // pads [72,96) & rows 14,15 stay zero
  }
  __syncthreads();

  // ---------------- P5: conv2 MFMA -> y2L [n][Y2S] f32, compile-time mtn ----------------
  {
    v8s bfr[3];
#pragma unroll
    for (int ks = 0; ks < 3; ++ks)
      bfr[ks] = *(v8s*)&y1b[(ml * 96 + ks * 32 + quad * 8) ^ SWZ(ml)];
    const int mt0 = (w < 2) ? 5 * w : 10 + 4 * (w - 2);
    const u16* w2base = w2bf + ml * 96 + quad * 8;

#define P5_RUN(MTN)                                                              \
  {                                                                              \
    v8s afA[3], afB[3];                                                          \
    _Pragma("unroll")                                                            \
    for (int ks = 0; ks < 3; ++ks)                                               \
      afA[ks] = *(const v8s*)(w2base + (mt0 * 16) * 96 + ks * 32);               \
    _Pragma("unroll")                                                            \
    for (int mi = 0; mi < (MTN); ++mi) {                                         \
      const int mt = mt0 + mi;                                                   \
      v4f a2 = (v4f){0.f, 0.f, 0.f, 0.f};                                        \
      if ((mi & 1) == 0) {                                                       \
        if (mi + 1 < (MTN)) {                                                    \
          _Pragma("unroll")                                                      \
          for (int ks = 0; ks < 3; ++ks)                                         \
            afB[ks] = *(const v8s*)(w2base + ((mt + 1) * 16) * 96 + ks * 32);    \
        }                                                                        \
        __builtin_amdgcn_s_setprio(1);                                           \
        _Pragma("unroll")                                                        \
        for (int ks = 0; ks < 3; ++ks)                                           \
          a2 = __builtin_amdgcn_mfma_f32_16x16x32_bf16(afA[ks], bfr[ks], a2, 0, 0, 0); \
        __builtin_amdgcn_s_setprio(0);                                           \
      } else {                                                                   \
        if (mi + 1 < (MTN)) {                                                    \
          _Pragma("unroll")                                                      \
          for (int ks = 0; ks < 3; ++ks)                                         \
            afA[ks] = *(const v8s*)(w2base + ((mt + 1) * 16) * 96 + ks * 32);    \
        }                                                                        \
        __builtin_amdgcn_s_setprio(1);                                           \
        _Pragma("unroll")                                                        \
        for (int ks = 0; ks < 3; ++ks)                                           \
          a2 = __builtin_amdgcn_mfma_f32_16x16x32_bf16(afB[ks], bfr[ks], a2, 0, 0, 0); \
        __builtin_amdgcn_s_setprio(0);                                           \
      }                                                                          \
      const int o0 = mt * 16 + quad * 4;                                         \
      const float4 bv = *(const float4*)(b2 + o0);                               \
      a2[0] += bv.x; a2[1] += bv.y; a2[2] += bv.z; a2[3] += bv.w;                \
      *(v4f*)&y2L[ml * Y2S + o0] = a2;                                           \
    }                                                                            \
  }

    if (w < 2) { P5_RUN(5) } else { P5_RUN(4) }
#undef P5_RUN
  }
  __syncthreads();

  // ---------------- P6: vectorized softmax over k(9); 112 threads x 4 nn cols ----------------
  if (t < 112) {
    const int gg = t / 14, n = t - gg * 14;
    float* bp = &y2L[n * Y2S + gg * 36];      // 16B-aligned (300, 36 mult of 4)
    v4f v[9];
    v4f m4 = (v4f){-1e30f, -1e30f, -1e30f, -1e30f};
#pragma unroll
    for (int k = 0; k < 9; ++k) {
      v[k] = *(v4f*)(bp + k * 4);
      m4 = __builtin_elementwise_max(m4, v[k]);
    }
    v4f sum = (v4f){0.f, 0.f, 0.f, 0.f};
#pragma unroll
    for (int k = 0; k < 9; ++k) {
#pragma unroll
      for (int j = 0; j < 4; ++j) v[k][j] = __expf(v[k][j] - m4[j]);
      sum[0] += v[k][0]; sum[1] += v[k][1]; sum[2] += v[k][2]; sum[3] += v[k][3];
    }
    v4f inv;
#pragma unroll
    for (int j = 0; j < 4; ++j) inv[j] = 1.f / sum[j];
#pragma unroll
    for (int k = 0; k < 9; ++k) {
      v4f o;
#pragma unroll
      for (int j = 0; j < 4; ++j) o[j] = v[k][j] * inv[j];
      *(v4f*)(bp + k * 4) = o;
    }
  }
  __syncthreads();

  // ---------------- P7: aggregation, packed-fp32 FMA, f32 window (no unpack) ----------------
  v2f accL[14], accH[14];   // (a0,a1) and (a2,a3) pairs -> feed P8 stores directly
#pragma unroll
  for (int n = 0; n < 14; ++n) {
    const v4f* wp = (const v4f*)&y2L[n * Y2S + g * 36];   // 9 x float4 (k-major, nn inside)
    v2f aL = (v2f){0.f, 0.f}, aH = (v2f){0.f, 0.f};
#pragma unroll
    for (int r = 0; r < 3; ++r) {
#pragma unroll
      for (int kj = 0; kj < 3; ++kj) {
        v4f wv = wp[r * 3 + kj];
        float x = win_f[r][n + kj];
        v2f xx = (v2f){x, x};
        aL = __builtin_elementwise_fma(xx, (v2f){wv[0], wv[1]}, aL);
        aH = __builtin_elementwise_fma(xx, (v2f){wv[2], wv[3]}, aH);
      }
    }
    accL[n] = aL; accH[n] = aH;
  }
  __syncthreads();   // y2L dead; tile (same LDS region) may now be written

  // ---------------- P8: 2-chunk LDS transpose + coalesced stores ----------------
  const int cl = c & 127;
  for (int ch = 0; ch < 2; ++ch) {
    if ((c >> 7) == ch) {
#pragma unroll
      for (int n = 0; n < 14; ++n) {
        *(v2f*)&tile[cl * 60 + 2 * n]      = accL[n];   // di=0 row
        *(v2f*)&tile[cl * 60 + 28 + 2 * n] = accH[n];   // di=1 row
      }
    }
    BARRIER_LDS();
#pragma unroll
    for (int it = 0; it < 7; ++it) {
      int f = t + it * 256;          // 0..1791, exactly covers the chunk
      int rr = f / 7, xi = f - rr * 7;
      int cg = ch * 128 + (rr >> 1), di = rr & 1;
      v4f val = *(v4f*)&tile[(rr >> 1) * 60 + di * 28 + xi * 4];
      *(v4f*)&out[((size_t)(b * CC + cg) * H2 + (size_t)(2 * i + di)) * W2D
                  + 28 * jt + xi * 4] = val;
    }
    if (ch == 0) BARRIER_LDS();      // protect chunk-1 writes; nothing after chunk 1
  }
}

extern "C" void kernel_launch(void* const* d_in, const int* in_sizes, int n_in,
                              void* d_out, int out_size, void* d_ws, size_t ws_size,
                              hipStream_t stream) {
  const float* in = (const float*)d_in[0];
  const float* W1 = (const float*)d_in[1];
  const float* b1 = (const float*)d_in[2];
  const float* W2 = (const float*)d_in[3];
  const float* b2 = (const float*)d_in[4];
  float* out = (float*)d_out;

  u16* w1bf = (u16*)d_ws;
  u16* w2bf = (u16*)((char*)d_ws + W2BF_OFF_B);

  const int B = in_sizes[0] / (CC * HH * WWID);

  kConvW<<<dim3(((W1BF_ELEMS + NO2 * 96) / 2 + 255) / 256), 256, 0, stream>>>(W1, W2, w1bf, w2bf);
  dim3 grid(WWID / PPB, HH, B);
  kFused<<<grid, 256, 0, stream>>>(in, w1bf, b1, w2bf, b2, out);
}

// Round 18
// 184.018 us; speedup vs baseline: 1.0721x; 1.0721x over previous
//
#include <hip/hip_runtime.h>

#define CC   256
#define HH   56
#define WWID 56
#define KIN1 1608
#define KP1  1632
#define NO1  72
#define NO2  288
#define PPB  14
#define H2   112
#define W2D  112

typedef unsigned short u16;
typedef unsigned int   u32;
typedef __attribute__((ext_vector_type(8))) short v8s;
typedef __attribute__((ext_vector_type(4))) float v4f;
typedef __attribute__((ext_vector_type(2))) float v2f;
typedef __attribute__((ext_vector_type(4))) unsigned short us4;

#define W1BF_ELEMS (80 * KP1)
#define W2BF_OFF_B 262144

// LDS layout (bytes). Total 32768. R18 = exact revert to R16 (session best,
// bench 184.8us / steady ~89us). R17 lesson (4th confirmation of the spill
// rule): f32 window registers (48 VGPR) live across the P2..P5 barrier span
// spilled to scratch (FETCH +6.5MB, WRITE +20MB) despite arch-VGPR staying 64.
// Long-lived state across the MFMA phases must stay packed bf16 (win_p, 24
// VGPR) or in LDS. Chain-local cut list is exhausted; structural rewrites are
// 0-for-6 this session -> hold R16.
#define LDS_TOTAL 32768
#define OFF_A 0        // rowmaxT [14][768] u16 (21504) -> partials [4][5][16][16] f32 (20480)
                       //   -> y2L [16][300] f32 (19200) -> tile [128][60] f32 (30720, spans A..C)
#define OFF_B 21504    // colmaxT [16][256] u16 (8192); overrun reads land in C (defined, discarded)
#define OFF_C 29696    // x1T / y1b [16][96] u16 (3072)

#define Y2S 300        // y2L row stride (f32): 300%32=12 -> rows spread over 8 banks

#define SWZ(row) (((row) & 7) << 3)   // u16-element XOR key per LDS row

__device__ __forceinline__ u16 f2b(float x) {
  u32 u = __float_as_uint(x);
  u = (u + 0x7FFFu + ((u >> 16) & 1u)) >> 16;   // RNE fp32->bf16
  return (u16)u;
}

// HW packed fp32->bf16 (RNE): dst[15:0]=cvt(lo), dst[31:16]=cvt(hi). 1 VALU op.
__device__ __forceinline__ u32 cvtpk(float lo, float hi) {
  u32 r;
  asm("v_cvt_pk_bf16_f32 %0, %1, %2" : "=v"(r) : "v"(lo), "v"(hi));
  return r;
}

// LDS-only barrier: no vmcnt drain (global stores stay in flight).
#define BARRIER_LDS()                                         \
  do {                                                        \
    asm volatile("s_waitcnt lgkmcnt(0)" ::: "memory");        \
    __builtin_amdgcn_s_barrier();                             \
    __builtin_amdgcn_sched_barrier(0);                        \
  } while (0)

// DPP max step on the VALU pipe (fuses to v_max_f32_dpp). ctrl literal.
#define DPPMAX(m, ctrl)                                                          \
  do {                                                                           \
    int _y = __builtin_amdgcn_update_dpp(0, __float_as_int(m), (ctrl), 0xF, 0xF, false); \
    (m) = fmaxf((m), __int_as_float(_y));                                        \
  } while (0)

// ---- weight conversion; W1 columns PERMUTED to K-layout:
//   phys [0,768)    = x2 region: kj*256 + c      <- orig 72 + c*3 + kj
//   phys [768,1536) = x3 region: r*256 + c       <- orig 840 + c*3 + r
//   phys [1536,1632)= x1 region: m72 (<72), pad  <- orig m72
__global__ void kConvW(const float* __restrict__ W1, const float* __restrict__ W2,
                       u16* __restrict__ w1bf, u16* __restrict__ w2bf) {
  int p = blockIdx.x * 256 + threadIdx.x;   // pair index
  int e0 = 2 * p;
  float v0 = 0.f, v1 = 0.f;
  if (e0 < W1BF_ELEMS) {
    int m = e0 / KP1, k = e0 - m * KP1;
    if (m < NO1) {
      const float* Wm = W1 + m * KIN1;
      if (k < 768) {
        int o = 72 + (k & 255) * 3 + (k >> 8);
        v0 = Wm[o]; v1 = Wm[o + 3];
      } else if (k < 1536) {
        int o = 840 + (k & 255) * 3 + ((k - 768) >> 8);
        v0 = Wm[o]; v1 = Wm[o + 3];
      } else {
        int t1 = k - 1536;
        if (t1 < NO1)     v0 = Wm[t1];
        if (t1 + 1 < NO1) v1 = Wm[t1 + 1];
      }
    }
    ((u32*)w1bf)[p] = (u32)f2b(v0) | ((u32)f2b(v1) << 16);
  } else {
    int i2 = e0 - W1BF_ELEMS;
    if (i2 < NO2 * 96) {
      int m = i2 / 96, k = i2 - m * 96;
      if (k < NO1) {
        v0 = W2[m * NO1 + k];
        if (k + 1 < NO1) v1 = W2[m * NO1 + k + 1];
      }
      ((u32*)w2bf)[i2 >> 1] = (u32)f2b(v0) | ((u32)f2b(v1) << 16);
    }
  }
}

__global__ __launch_bounds__(256, 4)
void kFused(const float* __restrict__ in, const u16* __restrict__ w1bf,
            const float* __restrict__ b1, const u16* __restrict__ w2bf,
            const float* __restrict__ b2, float* __restrict__ out) {
  __shared__ __align__(16) char lds[LDS_TOTAL];
  u16*   rowmaxT = (u16*)(lds + OFF_A);
  u16*   colmaxT = (u16*)(lds + OFF_B);
  u16*   x1T     = (u16*)(lds + OFF_C);   // later aliased as y1b
  float* partA   = (float*)(lds + OFF_A); // partials, then y2L
  float* y2L     = (float*)(lds + OFF_A);
  float* tile    = (float*)(lds + OFF_A); // out transpose [128][60] f32 (after P7 barrier)

  const int t  = threadIdx.x;
  // ---- XCD-aware block remap (round-2 win): XCD k owns batch b=k.
  const int L  = blockIdx.x + 4 * (blockIdx.y + 56 * blockIdx.z);
  const int jq = L >> 3;
  const int jt = jq & 3, i = jq >> 2, b = L & 7;
  const int c  = t;
  const int g  = c >> 5;
  const int gc = c & 31;
  const int w  = t >> 6, lane = t & 63;
  const int ml = lane & 15, quad = lane >> 4;

  // ---- zero x1T pads (swizzled): cols[72,96) rows 0..15, rows 14,15 cols[0,72).
  {
    u32* xu = (u32*)x1T;   // row stride 48 u32; u32-level XOR key = (row&7)<<2
    if (t < 132) {
#pragma unroll
      for (int rp2 = 0; rp2 < 2; ++rp2) {
        int idx = 2 * t + rp2;
        if (idx < 192) {
          int row = idx / 12;
          xu[(row * 48 + 36 + (idx - row * 12)) ^ ((row & 7) << 2)] = 0u;
        } else {
          int e = idx - 192, row = 14 + e / 36;
          xu[(row * 48 + (e % 36)) ^ ((row & 7) << 2)] = 0u;
        }
      }
    }
  }

  // ---------------- P1: ALL 3 rows' loads issued first (latency overlap), then process ----------------
  const float* rowbase0 = in + ((size_t)b * CC + c) * (HH * WWID);
  float l3[3][20];
#pragma unroll
  for (int r = 0; r < 3; ++r) {
    const int row = i - 1 + r;
    if (row < 0 || row >= HH) {
#pragma unroll
      for (int k = 0; k < 20; ++k) l3[r][k] = 0.f;
    } else {
      const float* rp = rowbase0 + row * WWID;
      if (jt == 0) {
        *(float4*)&l3[r][0]  = *(const float4*)(rp);
        *(float4*)&l3[r][4]  = *(const float4*)(rp + 4);
        *(float4*)&l3[r][8]  = *(const float4*)(rp + 8);
        *(float4*)&l3[r][12] = *(const float4*)(rp + 12);
        l3[r][16] = l3[r][17] = l3[r][18] = l3[r][19] = 0.f;
      } else if (jt == 3) {
        const float* q = rp + 40;
        *(float4*)&l3[r][0]  = *(const float4*)(q);
        *(float4*)&l3[r][4]  = *(const float4*)(q + 4);
        *(float4*)&l3[r][8]  = *(const float4*)(q + 8);
        *(float4*)&l3[r][12] = *(const float4*)(q + 12);
        l3[r][16] = l3[r][17] = l3[r][18] = l3[r][19] = 0.f;
      } else {
        const float* q = rp + ((jt == 1) ? 12 : 24);
        *(float4*)&l3[r][0]  = *(const float4*)(q);
        *(float4*)&l3[r][4]  = *(const float4*)(q + 4);
        *(float4*)&l3[r][8]  = *(const float4*)(q + 8);
        *(float4*)&l3[r][12] = *(const float4*)(q + 12);
        *(float4*)&l3[r][16] = *(const float4*)(q + 16);
      }
    }
  }

  u32 win_p[3][8];
  float colmax[16];
#pragma unroll
  for (int k = 0; k < 16; ++k) colmax[k] = -3.0e38f;

#pragma unroll
  for (int r = 0; r < 3; ++r) {
    float sc[16];
    if (jt == 0) {
      sc[0] = 0.f;
#pragma unroll
      for (int k = 1; k < 16; ++k) sc[k] = l3[r][k - 1];
    } else if (jt == 3) {
#pragma unroll
      for (int k = 0; k < 15; ++k) sc[k] = l3[r][k + 1];
      sc[15] = 0.f;
    } else if (jt == 1) {
#pragma unroll
      for (int k = 0; k < 16; ++k) sc[k] = l3[r][k + 1];
    } else {
#pragma unroll
      for (int k = 0; k < 16; ++k) sc[k] = l3[r][k + 3];
    }
    // colmax accumulate (x2 source: max over window rows = di axis)
#pragma unroll
    for (int k = 0; k < 16; ++k) colmax[k] = fmaxf(colmax[k], sc[k]);
    // rowmax (x3): sliding max over dj, bf16 transposed [n][r*256+c], swizzled
#pragma unroll
    for (int n = 0; n < 14; ++n) {
      float v = fmaxf(fmaxf(sc[n], sc[n + 1]), sc[n + 2]);
      rowmaxT[(n * 768 + r * 256 + c) ^ SWZ(n)] = (u16)cvtpk(v, v);
    }
    // x1 stage: 32-channel group max. DPP levels (VALU pipe) + one ds_swizzle.
#pragma unroll
    for (int col = 0; col < 16; ++col) {
      float m = sc[col];
      DPPMAX(m, 0xB1);   // quad_perm [1,0,3,2] : lane ^ 1
      DPPMAX(m, 0x4E);   // quad_perm [2,3,0,1] : lane ^ 2
      DPPMAX(m, 0x141);  // row_half_mirror     : merges 4-groups -> 8-group
      DPPMAX(m, 0x140);  // row_mirror          : merges 8-groups -> 16-group
      { int y = __builtin_amdgcn_ds_swizzle(__float_as_int(m), 0x401F);  // lane ^ 16
        m = fmaxf(m, __int_as_float(y)); }
      if (gc == col) {
        u16 mv = (u16)cvtpk(m, m);
#pragma unroll
        for (int kj = 0; kj < 3; ++kj) {
          const int n = col - kj;
          if (n >= 0 && n < 14)
            x1T[(n * 96 + g * 9 + r * 3 + kj) ^ SWZ(n)] = mv;
        }
      }
    }
    // pack window row to bf16 pairs — ONE v_cvt_pk_bf16_f32 per pair
#pragma unroll
    for (int k = 0; k < 8; ++k)
      win_p[r][k] = cvtpk(sc[2 * k], sc[2 * k + 1]);
  }
  // colmaxT write: [col][c], swizzled
#pragma unroll
  for (int col = 0; col < 16; ++col)
    colmaxT[(col * 256 + c) ^ SWZ(col)] = (u16)cvtpk(colmax[col], colmax[col]);
  __syncthreads();

  // ---------------- P2: conv1 MFMA, compile-time K-split per wave ----------------
  v4f acc[5];
#pragma unroll
  for (int mt = 0; mt < 5; ++mt) acc[mt] = (v4f){0.f, 0.f, 0.f, 0.f};

  auto loadB = [&](int ks) -> v8s {
    if (ks < 24) {
      int kj = ks >> 3, c0 = (ks & 7) * 32, rowi = ml + kj;
      return *(v8s*)&colmaxT[(rowi * 256 + c0 + quad * 8) ^ SWZ(rowi)];
    } else if (ks < 48) {
      return *(v8s*)&rowmaxT[(ml * 768 + (ks - 24) * 32 + quad * 8) ^ SWZ(ml)];
    } else {
      return *(v8s*)&x1T[(ml * 96 + (ks - 48) * 32 + quad * 8) ^ SWZ(ml)];
    }
  };

  // Literal bounds -> full unroll; loadB region branches fold; LDS/global
  // addresses become base + compile-time immediates; scheduler pipelines loads.
#define P2_RUN(KS0, KS1)                                                         \
  {                                                                              \
    v8s bf_c = loadB(KS0);                                                       \
    v8s af_c[5];                                                                 \
    _Pragma("unroll")                                                            \
    for (int mt = 0; mt < 5; ++mt)                                               \
      af_c[mt] = *(const v8s*)&w1bf[(mt * 16 + ml) * KP1 + (KS0) * 32 + quad * 8]; \
    _Pragma("unroll")                                                            \
    for (int ks = KS0; ks < KS1; ++ks) {                                         \
      v8s bf_n, af_n[5];                                                         \
      if (ks + 1 < KS1) {                                                        \
        bf_n = loadB(ks + 1);                                                    \
        _Pragma("unroll")                                                        \
        for (int mt = 0; mt < 5; ++mt)                                           \
          af_n[mt] = *(const v8s*)&w1bf[(mt * 16 + ml) * KP1 + (ks + 1) * 32 + quad * 8]; \
      }                                                                          \
      __builtin_amdgcn_s_setprio(1);                                             \
      _Pragma("unroll")                                                          \
      for (int mt = 0; mt < 5; ++mt)                                             \
        acc[mt] = __builtin_amdgcn_mfma_f32_16x16x32_bf16(af_c[mt], bf_c, acc[mt], 0, 0, 0); \
      __builtin_amdgcn_s_setprio(0);                                             \
      if (ks + 1 < KS1) {                                                        \
        bf_c = bf_n;                                                             \
        _Pragma("unroll")                                                        \
        for (int mt = 0; mt < 5; ++mt) af_c[mt] = af_n[mt];                      \
      }                                                                          \
    }                                                                            \
  }

  if (w == 0)      { P2_RUN(0, 13)  }
  else if (w == 1) { P2_RUN(13, 26) }
  else if (w == 2) { P2_RUN(26, 39) }
  else             { P2_RUN(39, 51) }
#undef P2_RUN
  __syncthreads();                // all LDS reads of colmaxT/rowmaxT/x1T complete

  // ---------------- P3: partials to LDS (aliases rowmaxT) ----------------
#pragma unroll
  for (int mt = 0; mt < 5; ++mt)
    *(v4f*)&partA[((w * 5 + mt) * 16 + ml) * 16 + quad * 4] = acc[mt];
  __syncthreads();

  // ---------------- P4: vectorized reduce -> y1b bf16 [n][96] (aliases x1T) ----------------
  u16* y1b = x1T;
  if (t < 252) {
    const int mb = t / 14, n = t - mb * 14;
    v4f s = *(const v4f*)(b1 + mb * 4);      // mb*4+3 <= 71 < 72
#pragma unroll
    for (int ww = 0; ww < 4; ++ww) {
      v4f p = *(v4f*)&partA[((ww * 5 + (mb >> 2)) * 16 + n) * 16 + (mb & 3) * 4];
      s[0] += p[0]; s[1] += p[1]; s[2] += p[2]; s[3] += p[3];
    }
    const u32 lo = cvtpk(s[0], s[1]), hi = cvtpk(s[2], s[3]);
    us4 h;
    h.x = (u16)lo; h.y = (u16)(lo >> 16); h.z = (u16)hi; h.w = (u16)(hi >> 16);
    *(us4*)&y1b[(n * 96 + mb * 4) ^ SWZ(n)] = h;   // pads [72,96) & rows 14,15 stay zero
  }
  __syncthreads();

  // ---------------- P5: conv2 MFMA -> y2L [n][Y2S] f32, compile-time mtn ----------------
  {
    v8s bfr[3];
#pragma unroll
    for (int ks = 0; ks < 3; ++ks)
      bfr[ks] = *(v8s*)&y1b[(ml * 96 + ks * 32 + quad * 8) ^ SWZ(ml)];
    const int mt0 = (w < 2) ? 5 * w : 10 + 4 * (w - 2);
    const u16* w2base = w2bf + ml * 96 + quad * 8;

#define P5_RUN(MTN)                                                              \
  {                                                                              \
    v8s afA[3], afB[3];                                                          \
    _Pragma("unroll")                                                            \
    for (int ks = 0; ks < 3; ++ks)                                               \
      afA[ks] = *(const v8s*)(w2base + (mt0 * 16) * 96 + ks * 32);               \
    _Pragma("unroll")                                                            \
    for (int mi = 0; mi < (MTN); ++mi) {                                         \
      const int mt = mt0 + mi;                                                   \
      v4f a2 = (v4f){0.f, 0.f, 0.f, 0.f};                                        \
      if ((mi & 1) == 0) {                                                       \
        if (mi + 1 < (MTN)) {                                                    \
          _Pragma("unroll")                                                      \
          for (int ks = 0; ks < 3; ++ks)                                         \
            afB[ks] = *(const v8s*)(w2base + ((mt + 1) * 16) * 96 + ks * 32);    \
        }                                                                        \
        __builtin_amdgcn_s_setprio(1);                                           \
        _Pragma("unroll")                                                        \
        for (int ks = 0; ks < 3; ++ks)                                           \
          a2 = __builtin_amdgcn_mfma_f32_16x16x32_bf16(afA[ks], bfr[ks], a2, 0, 0, 0); \
        __builtin_amdgcn_s_setprio(0);                                           \
      } else {                                                                   \
        if (mi + 1 < (MTN)) {                                                    \
          _Pragma("unroll")                                                      \
          for (int ks = 0; ks < 3; ++ks)                                         \
            afA[ks] = *(const v8s*)(w2base + ((mt + 1) * 16) * 96 + ks * 32);    \
        }                                                                        \
        __builtin_amdgcn_s_setprio(1);                                           \
        _Pragma("unroll")                                                        \
        for (int ks = 0; ks < 3; ++ks)                                           \
          a2 = __builtin_amdgcn_mfma_f32_16x16x32_bf16(afB[ks], bfr[ks], a2, 0, 0, 0); \
        __builtin_amdgcn_s_setprio(0);                                           \
      }                                                                          \
      const int o0 = mt * 16 + quad * 4;                                         \
      const float4 bv = *(const float4*)(b2 + o0);                               \
      a2[0] += bv.x; a2[1] += bv.y; a2[2] += bv.z; a2[3] += bv.w;                \
      *(v4f*)&y2L[ml * Y2S + o0] = a2;                                           \
    }                                                                            \
  }

    if (w < 2) { P5_RUN(5) } else { P5_RUN(4) }
#undef P5_RUN
  }
  __syncthreads();

  // ---------------- P6: vectorized softmax over k(9); 112 threads x 4 nn cols ----------------
  if (t < 112) {
    const int gg = t / 14, n = t - gg * 14;
    float* bp = &y2L[n * Y2S + gg * 36];      // 16B-aligned (300, 36 mult of 4)
    v4f v[9];
    v4f m4 = (v4f){-1e30f, -1e30f, -1e30f, -1e30f};
#pragma unroll
    for (int k = 0; k < 9; ++k) {
      v[k] = *(v4f*)(bp + k * 4);
      m4 = __builtin_elementwise_max(m4, v[k]);
    }
    v4f sum = (v4f){0.f, 0.f, 0.f, 0.f};
#pragma unroll
    for (int k = 0; k < 9; ++k) {
#pragma unroll
      for (int j = 0; j < 4; ++j) v[k][j] = __expf(v[k][j] - m4[j]);
      sum[0] += v[k][0]; sum[1] += v[k][1]; sum[2] += v[k][2]; sum[3] += v[k][3];
    }
    v4f inv;
#pragma unroll
    for (int j = 0; j < 4; ++j) inv[j] = 1.f / sum[j];
#pragma unroll
    for (int k = 0; k < 9; ++k) {
      v4f o;
#pragma unroll
      for (int j = 0; j < 4; ++j) o[j] = v[k][j] * inv[j];
      *(v4f*)(bp + k * 4) = o;
    }
  }
  __syncthreads();

  // ---------------- P7: aggregation, packed-fp32 FMA (v_pk_fma_f32) ----------------
  v2f accL[14], accH[14];   // (a0,a1) and (a2,a3) pairs -> feed P8 stores directly
#pragma unroll
  for (int n = 0; n < 14; ++n) {
    const v4f* wp = (const v4f*)&y2L[n * Y2S + g * 36];   // 9 x float4 (k-major, nn inside)
    v2f aL = (v2f){0.f, 0.f}, aH = (v2f){0.f, 0.f};
#pragma unroll
    for (int r = 0; r < 3; ++r) {
      float x0, x1, x2v;
      if ((n & 1) == 0) {
        u32 ua = win_p[r][n >> 1], ub = win_p[r][(n >> 1) + 1];
        x0  = __uint_as_float(ua << 16);
        x1  = __uint_as_float(ua & 0xffff0000u);
        x2v = __uint_as_float(ub << 16);
      } else {
        u32 ua = win_p[r][n >> 1], ub = win_p[r][(n >> 1) + 1];
        x0  = __uint_as_float(ua & 0xffff0000u);
        x1  = __uint_as_float(ub << 16);
        x2v = __uint_as_float(ub & 0xffff0000u);
      }
#pragma unroll
      for (int kj = 0; kj < 3; ++kj) {
        v4f wv = wp[r * 3 + kj];
        float x = (kj == 0) ? x0 : (kj == 1) ? x1 : x2v;
        v2f xx = (v2f){x, x};
        aL = __builtin_elementwise_fma(xx, (v2f){wv[0], wv[1]}, aL);
        aH = __builtin_elementwise_fma(xx, (v2f){wv[2], wv[3]}, aH);
      }
    }
    accL[n] = aL; accH[n] = aH;
  }
  __syncthreads();   // y2L dead; tile (same LDS region) may now be written

  // ---------------- P8: 2-chunk LDS transpose + coalesced stores ----------------
  const int cl = c & 127;
  for (int ch = 0; ch < 2; ++ch) {
    if ((c >> 7) == ch) {
#pragma unroll
      for (int n = 0; n < 14; ++n) {
        *(v2f*)&tile[cl * 60 + 2 * n]      = accL[n];   // di=0 row
        *(v2f*)&tile[cl * 60 + 28 + 2 * n] = accH[n];   // di=1 row
      }
    }
    BARRIER_LDS();
#pragma unroll
    for (int it = 0; it < 7; ++it) {
      int f = t + it * 256;          // 0..1791, exactly covers the chunk
      int rr = f / 7, xi = f - rr * 7;
      int cg = ch * 128 + (rr >> 1), di = rr & 1;
      v4f val = *(v4f*)&tile[(rr >> 1) * 60 + di * 28 + xi * 4];
      *(v4f*)&out[((size_t)(b * CC + cg) * H2 + (size_t)(2 * i + di)) * W2D
                  + 28 * jt + xi * 4] = val;
    }
    if (ch == 0) BARRIER_LDS();      // protect chunk-1 writes; nothing after chunk 1
  }
}

extern "C" void kernel_launch(void* const* d_in, const int* in_sizes, int n_in,
                              void* d_out, int out_size, void* d_ws, size_t ws_size,
                              hipStream_t stream) {
  const float* in = (const float*)d_in[0];
  const float* W1 = (const float*)d_in[1];
  const float* b1 = (const float*)d_in[2];
  const float* W2 = (const float*)d_in[3];
  const float* b2 = (const float*)d_in[4];
  float* out = (float*)d_out;

  u16* w1bf = (u16*)d_ws;
  u16* w2bf = (u16*)((char*)d_ws + W2BF_OFF_B);

  const int B = in_sizes[0] / (CC * HH * WWID);

  kConvW<<<dim3(((W1BF_ELEMS + NO2 * 96) / 2 + 255) / 256), 256, 0, stream>>>(W1, W2, w1bf, w2bf);
  dim3 grid(WWID / PPB, HH, B);
  kFused<<<grid, 256, 0, stream>>>(in, w1bf, b1, w2bf, b2, out);
}